// Round 9
// baseline (262.577 us; speedup 1.0000x reference)
//
#include <hip/hip_runtime.h>

// HeteGCNLayer on MI355X — round 17: xb intermediate deleted. main1 = binA ∥ prep;
// ft-GEMM stages A directly from x_f32 with in-register f2bf (r8 pattern, proven
// free), B via global_load_lds. Saves 153.6 MB of round-trip traffic.
// Sizes fixed by the reference: N_A=N_B=N_C=50000, E=800000, D_IN=256, D_OUT=128, T=64.
#define NA 50000
#define NE 800000
#define NBKT 196                  // ceil(50000 / 256) buckets of 256 rows
#define CAP 4608                  // padded bucket window (mean 4081, +8 sigma)
#define BSTRIDE (NBKT * CAP)      // 903,168 edge slots per relation

typedef unsigned int   u32;
typedef unsigned short u16;
typedef short s16x8 __attribute__((ext_vector_type(8)));
typedef float f32x4 __attribute__((ext_vector_type(4)));
typedef float f32x2 __attribute__((ext_vector_type(2)));

__device__ __forceinline__ u16 f2bf(float f) {
  u32 u = __float_as_uint(f);
  u += 0x7fffu + ((u >> 16) & 1u);   // round-to-nearest-even
  return (u16)(u >> 16);
}

// packed accumulate: 4x v_pk_fma_f32 per 16B of gathered bf16 (8 elems)
__device__ __forceinline__ void accp8(f32x2* a, uint4 q, float v) {
  f32x2 vv; vv[0] = v; vv[1] = v;
  f32x2 f;
  f[0] = __uint_as_float(q.x << 16); f[1] = __uint_as_float(q.x & 0xffff0000u);
  a[0] += vv * f;
  f[0] = __uint_as_float(q.y << 16); f[1] = __uint_as_float(q.y & 0xffff0000u);
  a[1] += vv * f;
  f[0] = __uint_as_float(q.z << 16); f[1] = __uint_as_float(q.z & 0xffff0000u);
  a[2] += vv * f;
  f[0] = __uint_as_float(q.w << 16); f[1] = __uint_as_float(q.w & 0xffff0000u);
  a[3] += vv * f;
}

// async global->LDS, 16 bytes per lane (m97 pattern)
__device__ __forceinline__ void glds16(const u16* g, u16* l) {
  __builtin_amdgcn_global_load_lds(
      (const __attribute__((address_space(1))) u32*)g,
      (__attribute__((address_space(3))) u32*)l, 16, 0, 0);
}

// inclusive scan of 256 per-thread values using wave shuffles; 3 barriers.
__device__ __forceinline__ void block_scan256(u32 own, u32* buf, int t) {
  u32 x = own;
  int lane = t & 63;
  #pragma unroll
  for (int off = 1; off < 64; off <<= 1) {
    u32 y = __shfl_up(x, off);
    if (lane >= off) x += y;
  }
  if (lane == 63) buf[t >> 6] = x;       // wave totals in buf[0..3]
  __syncthreads();
  u32 t0 = buf[0], t1 = buf[1], t2 = buf[2];
  int myw = t >> 6;
  u32 add = (myw > 0 ? t0 : 0u) + (myw > 1 ? t1 : 0u) + (myw > 2 ? t2 : 0u);
  __syncthreads();
  buf[t] = x + add;
  __syncthreads();
}

struct Rel4 { const int* row[4]; const int* col[4]; const float* val[4]; };

struct Prep {
  const float* src[10]; u16* dst[10];
  const float* wq; const float* wk; const float* wa; float* uvp;
};

struct FtArgs { const float* A[3]; const u16* Bt[3]; u16* C[3]; };

// frag-order Wcat + bias + output pointers for the fused epilogue
struct FuseW { const u16* Wf[3]; const float* bias[3]; float* out[3]; };

// ---------------------------------------------------------------------------
// k_main1: binA (y<4) ∥ prep (y==4: 10 weight emits + uv).
//   gcur holds per-bucket COUNTS (init 0 by memset); window base = bkt*CAP.
// ---------------------------------------------------------------------------
__global__ __launch_bounds__(256) void k_main1(Rel4 R, u32* __restrict__ gcur,
                                               uint2* __restrict__ pairs, Prep P) {
  __shared__ __align__(16) char smem[40960];
  const int gy = blockIdx.y;
  const int t = threadIdx.x;
  if (gy < 4) {
    // ================= binA role =================
    if (blockIdx.x >= 196) return;
    int rel = gy;
    int e0 = blockIdx.x * 4096;
    int nrem = min(4096, NE - e0);
    u32* sw0  = (u32*)smem;                       // [4096]
    u32* sval = sw0 + 4096;                       // [4096]
    unsigned char* sbkt = (unsigned char*)(sval + 4096);  // [4096]
    u32* hist  = (u32*)(sbkt + 4096);             // [256]
    u32* lscan = hist + 256;
    u32* cnt2  = lscan + 256;
    u32* gbase = cnt2 + 256;
    hist[t] = 0; cnt2[t] = 0;
    __syncthreads();
    const int* rr = R.row[rel];
    const int* cc = R.col[rel];
    const float* vl = R.val[rel];
    u32 w0[16]; u32 vv[16]; int bb[16];
    #pragma unroll
    for (int i = 0; i < 16; ++i) {
      int li = t + i * 256;
      bool ok = li < nrem;
      int idx = e0 + (ok ? li : 0);
      int r = ok ? rr[idx] : 0;
      int c = ok ? cc[idx] : 0;
      float v = ok ? vl[idx] : 0.f;
      u32 b = (u32)r >> 8;
      w0[i] = (u32)(c & 0xFFFF) | ((u32)(r & 255) << 16) | (b << 24);
      vv[i] = __float_as_uint(v);
      bb[i] = ok ? (int)b : -1;
      if (ok) atomicAdd(&hist[b], 1u);
    }
    __syncthreads();
    u32 own = hist[t];
    block_scan256(own, lscan, t);                 // 3 barriers
    gbase[t] = (u32)t * CAP + atomicAdd(&gcur[rel * 256 + t], own);
    #pragma unroll
    for (int i = 0; i < 16; ++i) {
      if (bb[i] >= 0) {
        int b = bb[i];
        u32 p = (lscan[b] - hist[b]) + atomicAdd(&cnt2[b], 1u);
        sw0[p] = w0[i]; sval[p] = vv[i]; sbkt[p] = (unsigned char)b;
      }
    }
    __syncthreads();
    uint2* Pp = pairs + (size_t)rel * BSTRIDE;
    #pragma unroll
    for (int i = 0; i < 16; ++i) {
      int p = t + i * 256;
      if (p < nrem) {
        int b = sbkt[p];
        u32 gd = gbase[b] + (u32)p - (lscan[b] - hist[b]);
        uint2 pr; pr.x = sw0[p]; pr.y = sval[p];
        Pp[gd] = pr;
      }
    }
  } else {
    // ================= prep role (weights + uv) =================
    const int bx = blockIdx.x;
    if (bx < 320) {
      // 10 weights x 32768 elems = 327,680 = 320 blocks x 1024
      #pragma unroll
      for (int rep = 0; rep < 4; ++rep) {
        int idx = bx * 1024 + rep * 256 + t;
        int w = idx >> 15;          // weight id 0..9
        int r = idx & 32767;
        if (w < 7) {
          int k = r & 255, n = r >> 8;
          P.dst[w][n * 256 + k] = f2bf(P.src[w][k * 128 + n]);
        } else {
          int e = r & 7, l = (r >> 3) & 63, jj = (r >> 9) & 7, ks = r >> 12;
          int n = jj * 16 + (l & 15);
          int k = ks * 32 + ((l >> 4) * 8) + e;
          P.dst[w][r] = f2bf(P.src[w][k * 128 + n]);
        }
      }
    } else if (bx == 320) {
      int d = t & 127, which = t >> 7;
      const float* w = which ? P.wq : P.wk;
      const float* a = P.wa + which * 64;
      float s = 0.f;
      for (int i = 0; i < 64; ++i) s += w[d * 64 + i] * a[i];
      P.uvp[which * 128 + d] = s;
    }
  }
}

// ---------------------------------------------------------------------------
// k_main2: binB (y<4) OVERLAPPED with feature GEMMs (y>=4).
//   ft role: 128x128 tile, BK=64. A staged from x_f32 with in-register f2bf
//   (padded [128][72] LDS); B via global_load_lds, linear [128][64].
// ---------------------------------------------------------------------------
__global__ __launch_bounds__(256) void k_main2(const u32* __restrict__ gcur,
    int* __restrict__ ofs_s, int* __restrict__ ofs_e,
    const uint2* __restrict__ pairs, u32* __restrict__ epak, FtArgs Ar) {
  __shared__ __align__(16) char smem[40960];
  const int gy = blockIdx.y;
  const int t = threadIdx.x;
  if (gy < 4) {
    // ================= binB role =================
    if (blockIdx.x >= 196) return;
    int rel = gy;
    int b = blockIdx.x;
    int base = b * CAP;
    int n = (int)gcur[rel * 256 + b];
    u32* sw0  = (u32*)smem;                       // [CAP]
    u32* sv   = sw0 + CAP;                        // [CAP]
    u32* hist = sv + CAP;                         // [256]
    u32* scan = hist + 256;
    u32* cur  = scan + 256;
    hist[t] = 0;
    __syncthreads();
    const uint2* P = pairs + (size_t)rel * BSTRIDE;
    for (int p = t; p < n; p += 256) {
      uint2 pr = P[base + p];
      sw0[p] = pr.x; sv[p] = pr.y;
      atomicAdd(&hist[(pr.x >> 16) & 255], 1u);
    }
    __syncthreads();
    u32 own = hist[t];
    block_scan256(own, scan, t);                  // 3 barriers
    u32 excl = scan[t] - own;
    cur[t] = excl;
    int r0 = b << 8;
    if (r0 + t < NA) {
      ofs_s[(size_t)rel * NA + r0 + t] = base + (int)excl;
      ofs_e[(size_t)rel * NA + r0 + t] = base + (int)(excl + own);
    }
    __syncthreads();
    u32* E = epak + (size_t)rel * BSTRIDE;
    for (int p = t; p < n; p += 256) {
      u32 w = sw0[p];
      int rl = (w >> 16) & 255;
      u32 d = atomicAdd(&cur[rl], 1u);
      E[base + (int)d] = (w & 0xFFFFu) | ((u32)f2bf(__uint_as_float(sv[p])) << 16);
    }
  } else {
    // ====== feature-GEMM role: A f32->bf16 reg staging, B glds linear ======
    u16* Al = (u16*)smem;            // [128][72] padded (manual staged A)
    u16* Bl = Al + 128 * 72;         // [128][64] linear (glds B)
    const int by = gy - 4;
    const int which = (by < 3) ? 0 : (by < 5 ? 1 : 2);
    const int col0 = (by - (which == 0 ? 0 : (which == 1 ? 3 : 5))) * 128;
    const int ldc = (which == 0) ? 384 : 256;
    const float* A = Ar.A[which];
    const u16* Bt = Ar.Bt[which] + (size_t)col0 * 256;
    u16* C = Ar.C[which] + col0;
    const int row0 = blockIdx.x * 128;
    const int w = t >> 6, l = t & 63;
    const int wr = (w >> 1) * 64, wc = (w & 1) * 64;
    const int sr = t >> 1, kb = (t & 1) * 32;
    f32x4 acc[4][4] = {};
    for (int kk = 0; kk < 4; ++kk) {
      // B: async glds, 4 chunks of 16B per thread
      #pragma unroll
      for (int q = 0; q < 4; ++q) {
        int c = q * 256 + t;
        int r = c >> 3, col8 = (c & 7) * 8;
        glds16(Bt + (size_t)r * 256 + kk * 64 + col8, Bl + c * 8);
      }
      // A: f32 loads + in-register f2bf (proven-free conversion, r8/r9)
      if (row0 + sr < NA) {
        const float* ap = A + (size_t)(row0 + sr) * 256 + kk * 64 + kb;
        #pragma unroll
        for (int h = 0; h < 2; ++h) {
          float f[16];
          #pragma unroll
          for (int i = 0; i < 4; ++i) {
            float4 v4 = *(const float4*)(ap + h * 16 + i * 4);
            f[4*i] = v4.x; f[4*i+1] = v4.y; f[4*i+2] = v4.z; f[4*i+3] = v4.w;
          }
          s16x8 v0, v1;
          #pragma unroll
          for (int i = 0; i < 8; ++i) { v0[i] = (short)f2bf(f[i]); v1[i] = (short)f2bf(f[i + 8]); }
          *(s16x8*)&Al[sr * 72 + kb + h * 16]     = v0;
          *(s16x8*)&Al[sr * 72 + kb + h * 16 + 8] = v1;
        }
      } else {
        s16x8 z = {0,0,0,0,0,0,0,0};
        #pragma unroll
        for (int h = 0; h < 4; ++h) *(s16x8*)&Al[sr * 72 + kb + h * 8] = z;
      }
      __syncthreads();
      #pragma unroll
      for (int ks = 0; ks < 2; ++ks) {
        s16x8 af[4], bfr[4];
        #pragma unroll
        for (int i = 0; i < 4; ++i)
          af[i] = *(const s16x8*)&Al[(wr + i * 16 + (l & 15)) * 72 + ks * 32 + (l >> 4) * 8];
        #pragma unroll
        for (int j = 0; j < 4; ++j)
          bfr[j] = *(const s16x8*)&Bl[(wc + j * 16 + (l & 15)) * 64 + ks * 32 + (l >> 4) * 8];
        #pragma unroll
        for (int i = 0; i < 4; ++i)
          #pragma unroll
          for (int j = 0; j < 4; ++j)
            acc[i][j] = __builtin_amdgcn_mfma_f32_16x16x32_bf16(af[i], bfr[j], acc[i][j], 0, 0, 0);
      }
      __syncthreads();
    }
    #pragma unroll
    for (int i = 0; i < 4; ++i)
      #pragma unroll
      for (int j = 0; j < 4; ++j)
        #pragma unroll
        for (int q = 0; q < 4; ++q) {
          int r = row0 + wr + i * 16 + (l >> 4) * 4 + q;
          if (r < NA) C[(size_t)r * ldc + wc + j * 16 + (l & 15)] = f2bf(acc[i][j][q]);
        }
  }
}

// ---------------------------------------------------------------------------
// Fused SpMM + output GEMM, grid (3125, 3). 4-byte edges.
// GROUP-PER-ROW (r14 loop: 4-deep gathers, u32 addressing, packed FMA).
// Out stores are nontemporal (write-once stream; keep L2 for gathers).
// ---------------------------------------------------------------------------
__global__ __launch_bounds__(256) void k_spmm(
    const int* __restrict__ ofs_s, const int* __restrict__ ofs_e,
    const u32* __restrict__ epak,
    const u16* __restrict__ ya, const u16* __restrict__ yb, const u16* __restrict__ yc,
    const float* __restrict__ uv, FuseW FW) {
  __shared__ u16 Asm[16 * 264];                // [16 rows][256 + 8 pad]
  int tid = threadIdx.x;
  int lane = tid & 63, wid = tid >> 6;
  int g = lane >> 4, gl = lane & 15;
  const u32 glb = (u32)gl * 16;                // byte offset within 256B feature row
  int lr = wid * 4 + g;                        // local row 0..15
  int row = blockIdx.x * 16 + lr;              // 3125 * 16 = 50000 exactly
  int gy = blockIdx.y;
  if (gy == 0) {
    const char* ybase = (const char*)yb;
    const char* cbase = (const char*)yc;
    f32x2 fb2[4] = {}; f32x2 fc2[4] = {};
    {
      int i = ofs_s[row], e = ofs_e[row];
      for (; i + 4 <= e; i += 4) {
        u32 p0 = epak[i], p1 = epak[i + 1], p2 = epak[i + 2], p3 = epak[i + 3];
        uint4 q0 = *(const uint4*)(ybase + (((p0 & 0xFFFFu) << 9) + glb));
        uint4 q1 = *(const uint4*)(ybase + (((p1 & 0xFFFFu) << 9) + glb));
        uint4 q2 = *(const uint4*)(ybase + (((p2 & 0xFFFFu) << 9) + glb));
        uint4 q3 = *(const uint4*)(ybase + (((p3 & 0xFFFFu) << 9) + glb));
        accp8(fb2, q0, __uint_as_float(p0 & 0xffff0000u));
        accp8(fb2, q1, __uint_as_float(p1 & 0xffff0000u));
        accp8(fb2, q2, __uint_as_float(p2 & 0xffff0000u));
        accp8(fb2, q3, __uint_as_float(p3 & 0xffff0000u));
      }
      for (; i < e; ++i) {
        u32 p0 = epak[i];
        uint4 q0 = *(const uint4*)(ybase + (((p0 & 0xFFFFu) << 9) + glb));
        accp8(fb2, q0, __uint_as_float(p0 & 0xffff0000u));
      }
    }
    {
      const u32* pr = epak + BSTRIDE;
      int i = ofs_s[NA + row], e = ofs_e[NA + row];
      for (; i + 4 <= e; i += 4) {
        u32 p0 = pr[i], p1 = pr[i + 1], p2 = pr[i + 2], p3 = pr[i + 3];
        uint4 q0 = *(const uint4*)(cbase + (((p0 & 0xFFFFu) << 9) + glb));
        uint4 q1 = *(const uint4*)(cbase + (((p1 & 0xFFFFu) << 9) + glb));
        uint4 q2 = *(const uint4*)(cbase + (((p2 & 0xFFFFu) << 9) + glb));
        uint4 q3 = *(const uint4*)(cbase + (((p3 & 0xFFFFu) << 9) + glb));
        accp8(fc2, q0, __uint_as_float(p0 & 0xffff0000u));
        accp8(fc2, q1, __uint_as_float(p1 & 0xffff0000u));
        accp8(fc2, q2, __uint_as_float(p2 & 0xffff0000u));
        accp8(fc2, q3, __uint_as_float(p3 & 0xffff0000u));
      }
      for (; i < e; ++i) {
        u32 p0 = pr[i];
        uint4 q0 = *(const uint4*)(cbase + (((p0 & 0xFFFFu) << 9) + glb));
        accp8(fc2, q0, __uint_as_float(p0 & 0xffff0000u));
      }
    }
    float fb[8], fc[8];
    #pragma unroll
    for (int j = 0; j < 8; ++j) { fb[j] = fb2[j >> 1][j & 1]; fc[j] = fc2[j >> 1][j & 1]; }
    uint4 sq = *(const uint4*)((const char*)ya + (u32)row * 768 + glb);
    float sf[8];
    sf[0] = __uint_as_float(sq.x << 16); sf[1] = __uint_as_float(sq.x & 0xffff0000u);
    sf[2] = __uint_as_float(sq.y << 16); sf[3] = __uint_as_float(sq.y & 0xffff0000u);
    sf[4] = __uint_as_float(sq.z << 16); sf[5] = __uint_as_float(sq.z & 0xffff0000u);
    sf[6] = __uint_as_float(sq.w << 16); sf[7] = __uint_as_float(sq.w & 0xffff0000u);
    float pb = 0.f, pc = 0.f, pq = 0.f;
    const float* up = uv + gl * 8;
    const float* vp = uv + 128 + gl * 8;
    #pragma unroll
    for (int j = 0; j < 8; ++j) {
      pb += fb[j] * up[j];
      pc += fc[j] * up[j];
      pq += sf[j] * vp[j];
    }
    #pragma unroll
    for (int off = 1; off < 16; off <<= 1) {
      pb += __shfl_xor(pb, off);
      pc += __shfl_xor(pc, off);
      pq += __shfl_xor(pq, off);
    }
    float eb = pb + pq, ec = pc + pq;
    eb = eb > 0.f ? eb : (expf(eb) - 1.f);
    ec = ec > 0.f ? ec : (expf(ec) - 1.f);
    float m = fmaxf(eb, ec);
    float p0 = expf(eb - m), p1 = expf(ec - m);
    float inv = 1.f / (p0 + p1);
    float a0 = p0 * inv, a1 = p1 * inv;
    s16x8 av;
    #pragma unroll
    for (int j = 0; j < 8; ++j) av[j] = (short)f2bf(a0 * fb[j] + a1 * fc[j]);
    *(s16x8*)&Asm[lr * 264 + gl * 8] = av;                 // agg -> cols 0..127
    *(s16x8*)&Asm[lr * 264 + 128 + gl * 8] = *(s16x8*)&sq; // self -> cols 128..255
  } else {
    const int which = gy - 1;                 // 0 -> ba, 1 -> ca
    const int* os = ofs_s + (2 + which) * NA;
    const int* oe = ofs_e + (2 + which) * NA;
    const u32* pr = epak + (size_t)(2 + which) * BSTRIDE;
    const char* fbase = (const char*)ya + (which ? 512 : 256);  // ld = 768 B
    const char* selfp = (const char*)(which ? yc : yb);         // ld = 512 B
    f32x2 fa2[4] = {};
    int i = os[row], e = oe[row];
    for (; i + 4 <= e; i += 4) {
      u32 p0 = pr[i], p1 = pr[i + 1], p2 = pr[i + 2], p3 = pr[i + 3];
      uint4 q0 = *(const uint4*)(fbase + ((p0 & 0xFFFFu) * 768u + glb));
      uint4 q1 = *(const uint4*)(fbase + ((p1 & 0xFFFFu) * 768u + glb));
      uint4 q2 = *(const uint4*)(fbase + ((p2 & 0xFFFFu) * 768u + glb));
      uint4 q3 = *(const uint4*)(fbase + ((p3 & 0xFFFFu) * 768u + glb));
      accp8(fa2, q0, __uint_as_float(p0 & 0xffff0000u));
      accp8(fa2, q1, __uint_as_float(p1 & 0xffff0000u));
      accp8(fa2, q2, __uint_as_float(p2 & 0xffff0000u));
      accp8(fa2, q3, __uint_as_float(p3 & 0xffff0000u));
    }
    for (; i < e; ++i) {
      u32 p0 = pr[i];
      uint4 q0 = *(const uint4*)(fbase + ((p0 & 0xFFFFu) * 768u + glb));
      accp8(fa2, q0, __uint_as_float(p0 & 0xffff0000u));
    }
    s16x8 av;
    #pragma unroll
    for (int j = 0; j < 8; ++j) av[j] = (short)f2bf(fa2[j >> 1][j & 1]);
    *(s16x8*)&Asm[lr * 264 + gl * 8] = av;                 // agg -> cols 0..127
    *(s16x8*)&Asm[lr * 264 + 128 + gl * 8] =
        *(const s16x8*)(selfp + (u32)row * 512 + 256 + glb); // self (already bf16)
  }
  __syncthreads();
  // ---------------- fused output GEMM epilogue ----------------
  // wave `wid` computes output cols [wid*32, wid*32+32) for all 16 rows.
  const u16* Wf = FW.Wf[gy];
  const float* bias = FW.bias[gy];
  float* outp = FW.out[gy];
  const int j0 = wid * 2, j1 = wid * 2 + 1;
  f32x4 acc0 = {0.f, 0.f, 0.f, 0.f}, acc1 = {0.f, 0.f, 0.f, 0.f};
  #pragma unroll
  for (int ks = 0; ks < 8; ++ks) {
    s16x8 a = *(const s16x8*)&Asm[(lane & 15) * 264 + ks * 32 + (lane >> 4) * 8];
    s16x8 b0 = *(const s16x8*)(Wf + ((size_t)(ks * 8 + j0) * 64 + lane) * 8);
    s16x8 b1 = *(const s16x8*)(Wf + ((size_t)(ks * 8 + j1) * 64 + lane) * 8);
    acc0 = __builtin_amdgcn_mfma_f32_16x16x32_bf16(a, b0, acc0, 0, 0, 0);
    acc1 = __builtin_amdgcn_mfma_f32_16x16x32_bf16(a, b1, acc1, 0, 0, 0);
  }
  const int c0 = j0 * 16 + (lane & 15), c1 = j1 * 16 + (lane & 15);
  const float b0v = bias[c0], b1v = bias[c1];
  const int rbase = blockIdx.x * 16 + (lane >> 4) * 4;
  #pragma unroll
  for (int q = 0; q < 4; ++q) {
    __builtin_nontemporal_store(acc0[q] + b0v, &outp[(size_t)(rbase + q) * 128 + c0]);
    __builtin_nontemporal_store(acc1[q] + b1v, &outp[(size_t)(rbase + q) * 128 + c1]);
  }
}

// ---------------------------------------------------------------------------
extern "C" void kernel_launch(void* const* d_in, const int* in_sizes, int n_in,
                              void* d_out, int out_size, void* d_ws, size_t ws_size,
                              hipStream_t stream) {
  const float* x_a = (const float*)d_in[0];
  const float* x_b = (const float*)d_in[1];
  const float* x_c = (const float*)d_in[2];
  const int* row_ab = (const int*)d_in[3];
  const int* col_ab = (const int*)d_in[4];
  const float* val_ab = (const float*)d_in[5];
  const int* row_ac = (const int*)d_in[6];
  const int* col_ac = (const int*)d_in[7];
  const float* val_ac = (const float*)d_in[8];
  const int* row_ba = (const int*)d_in[9];
  const int* col_ba = (const int*)d_in[10];
  const float* val_ba = (const float*)d_in[11];
  const int* row_ca = (const int*)d_in[12];
  const int* col_ca = (const int*)d_in[13];
  const float* val_ca = (const float*)d_in[14];
  const float* w_self_a = (const float*)d_in[15];
  const float* w_self_b = (const float*)d_in[16];
  const float* w_self_c = (const float*)d_in[17];
  const float* W_ab = (const float*)d_in[18];
  const float* W_ac = (const float*)d_in[19];
  const float* W_ba = (const float*)d_in[20];
  const float* W_ca = (const float*)d_in[21];
  const float* bias_a = (const float*)d_in[22];
  const float* bias_b = (const float*)d_in[23];
  const float* bias_c = (const float*)d_in[24];
  const float* w_cat_a = (const float*)d_in[25];
  const float* w_cat_b = (const float*)d_in[26];
  const float* w_cat_c = (const float*)d_in[27];
  const float* w_query_a = (const float*)d_in[28];
  const float* w_keys_a = (const float*)d_in[29];
  const float* w_att_a = (const float*)d_in[30];

  float* out = (float*)d_out;

  // ---- workspace layout ----
  char* ws = (char*)d_ws;
  size_t off_b = 0;
  auto walloc = [&](size_t bytes) {
    void* p = ws + off_b;
    off_b = (off_b + bytes + 255) & ~(size_t)255;
    return p;
  };
  u16* ya = (u16*)walloc((size_t)NA * 384 * 2);     // [self_a | fa_ba | fa_ca]
  u16* yb = (u16*)walloc((size_t)NA * 256 * 2);     // [fb | self_b]
  u16* yc = (u16*)walloc((size_t)NA * 256 * 2);     // [fc | self_c]
  int* ofs_s = (int*)walloc((size_t)4 * NA * 4);
  int* ofs_e = (int*)walloc((size_t)4 * NA * 4);
  u32* gcur = (u32*)walloc((size_t)4 * 256 * 4);
  uint2* pairs = (uint2*)walloc((size_t)4 * BSTRIDE * 8);
  u32* epak = (u32*)walloc((size_t)4 * BSTRIDE * 4);
  u16* Wa_t = (u16*)walloc((size_t)384 * 256 * 2);
  u16* Wb_t = (u16*)walloc((size_t)256 * 256 * 2);
  u16* Wc_t = (u16*)walloc((size_t)256 * 256 * 2);
  u16* Wcat_a = (u16*)walloc((size_t)128 * 256 * 2);  // frag-order
  u16* Wcat_b = (u16*)walloc((size_t)128 * 256 * 2);  // frag-order
  u16* Wcat_c = (u16*)walloc((size_t)128 * 256 * 2);  // frag-order
  float* uvbuf = (float*)walloc(256 * 4);

  // relation order: 0=ab, 1=ac, 2=ba, 3=ca
  Rel4 R;
  R.row[0] = row_ab; R.col[0] = col_ab; R.val[0] = val_ab;
  R.row[1] = row_ac; R.col[1] = col_ac; R.val[1] = val_ac;
  R.row[2] = row_ba; R.col[2] = col_ba; R.val[2] = val_ba;
  R.row[3] = row_ca; R.col[3] = col_ca; R.val[3] = val_ca;

  Prep P;
  P.src[0] = w_self_a; P.dst[0] = Wa_t;
  P.src[1] = W_ba;     P.dst[1] = Wa_t + 128 * 256;
  P.src[2] = W_ca;     P.dst[2] = Wa_t + 256 * 256;
  P.src[3] = W_ab;     P.dst[3] = Wb_t;
  P.src[4] = w_self_b; P.dst[4] = Wb_t + 128 * 256;
  P.src[5] = W_ac;     P.dst[5] = Wc_t;
  P.src[6] = w_self_c; P.dst[6] = Wc_t + 128 * 256;
  P.src[7] = w_cat_a;  P.dst[7] = Wcat_a;   // frag-order emit
  P.src[8] = w_cat_b;  P.dst[8] = Wcat_b;   // frag-order emit
  P.src[9] = w_cat_c;  P.dst[9] = Wcat_c;   // frag-order emit
  P.wq = w_query_a; P.wk = w_keys_a; P.wa = w_att_a; P.uvp = uvbuf;

  // ---- gcur counts -> 0 ----
  hipMemsetAsync(gcur, 0, (size_t)4 * 256 * 4, stream);

  // ---- binA ∥ prep (weights + uv) ----
  dim3 g1(321, 5);
  k_main1<<<g1, 256, 0, stream>>>(R, gcur, pairs, P);

  // ---- binB OVERLAPPED with all 7 feature-GEMM col-tiles (f32 A direct) ----
  FtArgs FA;
  FA.A[0] = x_a; FA.A[1] = x_b; FA.A[2] = x_c;
  FA.Bt[0] = Wa_t; FA.Bt[1] = Wb_t; FA.Bt[2] = Wc_t;
  FA.C[0] = ya; FA.C[1] = yb; FA.C[2] = yc;
  dim3 g2(391, 11);
  k_main2<<<g2, 256, 0, stream>>>(gcur, ofs_s, ofs_e, pairs, epak, FA);

  // ---- fused SpMMs + output GEMMs ----
  FuseW FW;
  FW.Wf[0] = Wcat_a; FW.Wf[1] = Wcat_b; FW.Wf[2] = Wcat_c;
  FW.bias[0] = bias_a; FW.bias[1] = bias_b; FW.bias[2] = bias_c;
  FW.out[0] = out; FW.out[1] = out + (size_t)NA * 128; FW.out[2] = out + (size_t)NA * 128 * 2;
  dim3 gs(3125, 3);
  k_spmm<<<gs, 256, 0, stream>>>(ofs_s, ofs_e, epak, ya, yb, yc, uvbuf, FW);
}

// Round 10
// 258.258 us; speedup vs baseline: 1.0167x; 1.0167x over previous
//
#include <hip/hip_runtime.h>

// HeteGCNLayer on MI355X — round 18: restore round-16 optimum (best measured,
// 259.7 µs) + NT loads for the conv slice's single-touch x stream.
// Sizes fixed by the reference: N_A=N_B=N_C=50000, E=800000, D_IN=256, D_OUT=128, T=64.
#define NA 50000
#define NE 800000
#define NBKT 196                  // ceil(50000 / 256) buckets of 256 rows
#define CAP 4608                  // padded bucket window (mean 4081, +8 sigma)
#define BSTRIDE (NBKT * CAP)      // 903,168 edge slots per relation

typedef unsigned int   u32;
typedef unsigned short u16;
typedef short s16x8 __attribute__((ext_vector_type(8)));
typedef float f32x4 __attribute__((ext_vector_type(4)));
typedef float f32x2 __attribute__((ext_vector_type(2)));

__device__ __forceinline__ u16 f2bf(float f) {
  u32 u = __float_as_uint(f);
  u += 0x7fffu + ((u >> 16) & 1u);   // round-to-nearest-even
  return (u16)(u >> 16);
}

// packed accumulate: 4x v_pk_fma_f32 per 16B of gathered bf16 (8 elems)
__device__ __forceinline__ void accp8(f32x2* a, uint4 q, float v) {
  f32x2 vv; vv[0] = v; vv[1] = v;
  f32x2 f;
  f[0] = __uint_as_float(q.x << 16); f[1] = __uint_as_float(q.x & 0xffff0000u);
  a[0] += vv * f;
  f[0] = __uint_as_float(q.y << 16); f[1] = __uint_as_float(q.y & 0xffff0000u);
  a[1] += vv * f;
  f[0] = __uint_as_float(q.z << 16); f[1] = __uint_as_float(q.z & 0xffff0000u);
  a[2] += vv * f;
  f[0] = __uint_as_float(q.w << 16); f[1] = __uint_as_float(q.w & 0xffff0000u);
  a[3] += vv * f;
}

// async global->LDS, 16 bytes per lane (m97 pattern)
__device__ __forceinline__ void glds16(const u16* g, u16* l) {
  __builtin_amdgcn_global_load_lds(
      (const __attribute__((address_space(1))) u32*)g,
      (__attribute__((address_space(3))) u32*)l, 16, 0, 0);
}

// inclusive scan of 256 per-thread values using wave shuffles; 3 barriers.
__device__ __forceinline__ void block_scan256(u32 own, u32* buf, int t) {
  u32 x = own;
  int lane = t & 63;
  #pragma unroll
  for (int off = 1; off < 64; off <<= 1) {
    u32 y = __shfl_up(x, off);
    if (lane >= off) x += y;
  }
  if (lane == 63) buf[t >> 6] = x;       // wave totals in buf[0..3]
  __syncthreads();
  u32 t0 = buf[0], t1 = buf[1], t2 = buf[2];
  int myw = t >> 6;
  u32 add = (myw > 0 ? t0 : 0u) + (myw > 1 ? t1 : 0u) + (myw > 2 ? t2 : 0u);
  __syncthreads();
  buf[t] = x + add;
  __syncthreads();
}

struct Rel4 { const int* row[4]; const int* col[4]; const float* val[4]; };

struct Prep {
  const float* src[10]; u16* dst[10];
  const float* wq; const float* wk; const float* wa; float* uvp;
};

struct ConvArgs { const float* x[3]; u16* xb; };

struct FtArgs { const u16* A[3]; const u16* Bt[3]; u16* C[3]; };

// frag-order Wcat + bias + output pointers for the fused epilogue
struct FuseW { const u16* Wf[3]; const float* bias[3]; float* out[3]; };

// ---------------------------------------------------------------------------
// k_main1: binA (y<4) ∥ x->bf16 conversion (y in 4..10) ∥ prep (y==11).
//   gcur holds per-bucket COUNTS (init 0 by memset); window base = bkt*CAP.
// ---------------------------------------------------------------------------
__global__ __launch_bounds__(256) void k_main1(Rel4 R, u32* __restrict__ gcur,
                                               uint2* __restrict__ pairs, ConvArgs CA,
                                               Prep P) {
  __shared__ __align__(16) char smem[40960];
  const int gy = blockIdx.y;
  const int t = threadIdx.x;
  if (gy < 4) {
    // ================= binA role =================
    if (blockIdx.x >= 196) return;
    int rel = gy;
    int e0 = blockIdx.x * 4096;
    int nrem = min(4096, NE - e0);
    u32* sw0  = (u32*)smem;                       // [4096]
    u32* sval = sw0 + 4096;                       // [4096]
    unsigned char* sbkt = (unsigned char*)(sval + 4096);  // [4096]
    u32* hist  = (u32*)(sbkt + 4096);             // [256]
    u32* lscan = hist + 256;
    u32* cnt2  = lscan + 256;
    u32* gbase = cnt2 + 256;
    hist[t] = 0; cnt2[t] = 0;
    __syncthreads();
    const int* rr = R.row[rel];
    const int* cc = R.col[rel];
    const float* vl = R.val[rel];
    u32 w0[16]; u32 vv[16]; int bb[16];
    #pragma unroll
    for (int i = 0; i < 16; ++i) {
      int li = t + i * 256;
      bool ok = li < nrem;
      int idx = e0 + (ok ? li : 0);
      int r = ok ? rr[idx] : 0;
      int c = ok ? cc[idx] : 0;
      float v = ok ? vl[idx] : 0.f;
      u32 b = (u32)r >> 8;
      w0[i] = (u32)(c & 0xFFFF) | ((u32)(r & 255) << 16) | (b << 24);
      vv[i] = __float_as_uint(v);
      bb[i] = ok ? (int)b : -1;
      if (ok) atomicAdd(&hist[b], 1u);
    }
    __syncthreads();
    u32 own = hist[t];
    block_scan256(own, lscan, t);                 // 3 barriers
    gbase[t] = (u32)t * CAP + atomicAdd(&gcur[rel * 256 + t], own);
    #pragma unroll
    for (int i = 0; i < 16; ++i) {
      if (bb[i] >= 0) {
        int b = bb[i];
        u32 p = (lscan[b] - hist[b]) + atomicAdd(&cnt2[b], 1u);
        sw0[p] = w0[i]; sval[p] = vv[i]; sbkt[p] = (unsigned char)b;
      }
    }
    __syncthreads();
    uint2* Pp = pairs + (size_t)rel * BSTRIDE;
    #pragma unroll
    for (int i = 0; i < 16; ++i) {
      int p = t + i * 256;
      if (p < nrem) {
        int b = sbkt[p];
        u32 gd = gbase[b] + (u32)p - (lscan[b] - hist[b]);
        uint2 pr; pr.x = sw0[p]; pr.y = sval[p];
        Pp[gd] = pr;
      }
    }
  } else if (gy < 11) {
    // ================= x -> bf16 conversion role =================
    const size_t TOT = 38400000;                  // 3 * 50000 * 256
    const size_t TSZ = 12800000;                  // per tensor
    size_t base = ((size_t)(gy - 4) * 391 + blockIdx.x) * 16384 + (size_t)t * 8;
    #pragma unroll
    for (int it = 0; it < 8; ++it) {
      size_t g = base + (size_t)it * 2048;
      if (g < TOT) {
        int which = (g >= 2 * TSZ) ? 2 : (g >= TSZ ? 1 : 0);
        size_t off = g - (size_t)which * TSZ;
        const float* sp = CA.x[which] + off;
        f32x4 v0 = __builtin_nontemporal_load((const f32x4*)sp);
        f32x4 v1 = __builtin_nontemporal_load((const f32x4*)(sp + 4));
        s16x8 o;
        o[0] = (short)f2bf(v0[0]); o[1] = (short)f2bf(v0[1]);
        o[2] = (short)f2bf(v0[2]); o[3] = (short)f2bf(v0[3]);
        o[4] = (short)f2bf(v1[0]); o[5] = (short)f2bf(v1[1]);
        o[6] = (short)f2bf(v1[2]); o[7] = (short)f2bf(v1[3]);
        *(s16x8*)(CA.xb + g) = o;
      }
    }
  } else {
    // ================= prep role (weights + uv) =================
    const int bx = blockIdx.x;
    if (bx < 320) {
      // 10 weights x 32768 elems = 327,680 = 320 blocks x 1024
      #pragma unroll
      for (int rep = 0; rep < 4; ++rep) {
        int idx = bx * 1024 + rep * 256 + t;
        int w = idx >> 15;          // weight id 0..9
        int r = idx & 32767;
        if (w < 7) {
          int k = r & 255, n = r >> 8;
          P.dst[w][n * 256 + k] = f2bf(P.src[w][k * 128 + n]);
        } else {
          int e = r & 7, l = (r >> 3) & 63, jj = (r >> 9) & 7, ks = r >> 12;
          int n = jj * 16 + (l & 15);
          int k = ks * 32 + ((l >> 4) * 8) + e;
          P.dst[w][r] = f2bf(P.src[w][k * 128 + n]);
        }
      }
    } else if (bx == 320) {
      int d = t & 127, which = t >> 7;
      const float* w = which ? P.wq : P.wk;
      const float* a = P.wa + which * 64;
      float s = 0.f;
      for (int i = 0; i < 64; ++i) s += w[d * 64 + i] * a[i];
      P.uvp[which * 128 + d] = s;
    }
  }
}

// ---------------------------------------------------------------------------
// k_main2: binB (y<4) OVERLAPPED with feature GEMMs (y>=4).
//   ft role: m97 structure — 128x128 tile, BK=64, LINEAR LDS [128][64],
//   global_load_lds dwordx4 staging (4 calls A + 4 calls B per K-step).
// ---------------------------------------------------------------------------
__global__ __launch_bounds__(256) void k_main2(const u32* __restrict__ gcur,
    int* __restrict__ ofs_s, int* __restrict__ ofs_e,
    const uint2* __restrict__ pairs, u32* __restrict__ epak, FtArgs Ar) {
  __shared__ __align__(16) char smem[40960];
  const int gy = blockIdx.y;
  const int t = threadIdx.x;
  if (gy < 4) {
    // ================= binB role =================
    if (blockIdx.x >= 196) return;
    int rel = gy;
    int b = blockIdx.x;
    int base = b * CAP;
    int n = (int)gcur[rel * 256 + b];
    u32* sw0  = (u32*)smem;                       // [CAP]
    u32* sv   = sw0 + CAP;                        // [CAP]
    u32* hist = sv + CAP;                         // [256]
    u32* scan = hist + 256;
    u32* cur  = scan + 256;
    hist[t] = 0;
    __syncthreads();
    const uint2* P = pairs + (size_t)rel * BSTRIDE;
    for (int p = t; p < n; p += 256) {
      uint2 pr = P[base + p];
      sw0[p] = pr.x; sv[p] = pr.y;
      atomicAdd(&hist[(pr.x >> 16) & 255], 1u);
    }
    __syncthreads();
    u32 own = hist[t];
    block_scan256(own, scan, t);                  // 3 barriers
    u32 excl = scan[t] - own;
    cur[t] = excl;
    int r0 = b << 8;
    if (r0 + t < NA) {
      ofs_s[(size_t)rel * NA + r0 + t] = base + (int)excl;
      ofs_e[(size_t)rel * NA + r0 + t] = base + (int)(excl + own);
    }
    __syncthreads();
    u32* E = epak + (size_t)rel * BSTRIDE;
    for (int p = t; p < n; p += 256) {
      u32 w = sw0[p];
      int rl = (w >> 16) & 255;
      u32 d = atomicAdd(&cur[rl], 1u);
      E[base + (int)d] = (w & 0xFFFFu) | ((u32)f2bf(__uint_as_float(sv[p])) << 16);
    }
  } else {
    // ====== feature-GEMM role: m97-style glds staging, linear LDS ======
    u16* Asl = (u16*)smem;           // [128][64] linear
    u16* Bsl = Asl + 128 * 64;       // [128][64] linear
    const int by = gy - 4;
    const int which = (by < 3) ? 0 : (by < 5 ? 1 : 2);
    const int col0 = (by - (which == 0 ? 0 : (which == 1 ? 3 : 5))) * 128;
    const int ldc = (which == 0) ? 384 : 256;
    const u16* A = Ar.A[which];
    const u16* Bt = Ar.Bt[which] + (size_t)col0 * 256;
    u16* C = Ar.C[which] + col0;
    const int row0 = blockIdx.x * 128;
    const int w = t >> 6, l = t & 63;
    const int wr = (w >> 1) * 64, wc = (w & 1) * 64;
    f32x4 acc[4][4] = {};
    for (int kk = 0; kk < 4; ++kk) {
      #pragma unroll
      for (int q = 0; q < 4; ++q) {
        int c = q * 256 + t;
        int r = c >> 3, col8 = (c & 7) * 8;
        int gr = row0 + r; gr = gr < NA ? gr : NA - 1;   // clamp (writes guarded)
        glds16(A + (size_t)gr * 256 + kk * 64 + col8, Asl + c * 8);
        glds16(Bt + (size_t)r * 256 + kk * 64 + col8, Bsl + c * 8);
      }
      __syncthreads();
      #pragma unroll
      for (int ks = 0; ks < 2; ++ks) {
        s16x8 af[4], bfr[4];
        #pragma unroll
        for (int i = 0; i < 4; ++i)
          af[i] = *(const s16x8*)&Asl[(wr + i * 16 + (l & 15)) * 64 + ks * 32 + (l >> 4) * 8];
        #pragma unroll
        for (int j = 0; j < 4; ++j)
          bfr[j] = *(const s16x8*)&Bsl[(wc + j * 16 + (l & 15)) * 64 + ks * 32 + (l >> 4) * 8];
        #pragma unroll
        for (int i = 0; i < 4; ++i)
          #pragma unroll
          for (int j = 0; j < 4; ++j)
            acc[i][j] = __builtin_amdgcn_mfma_f32_16x16x32_bf16(af[i], bfr[j], acc[i][j], 0, 0, 0);
      }
      __syncthreads();
    }
    #pragma unroll
    for (int i = 0; i < 4; ++i)
      #pragma unroll
      for (int j = 0; j < 4; ++j)
        #pragma unroll
        for (int q = 0; q < 4; ++q) {
          int r = row0 + wr + i * 16 + (l >> 4) * 4 + q;
          if (r < NA) C[(size_t)r * ldc + wc + j * 16 + (l & 15)] = f2bf(acc[i][j][q]);
        }
  }
}

// ---------------------------------------------------------------------------
// Fused SpMM + output GEMM, grid (3125, 3). 4-byte edges.
// GROUP-PER-ROW (r14 loop: 4-deep gathers, u32 addressing, packed FMA).
// Out stores are nontemporal (write-once stream; keep L2 for gathers).
// ---------------------------------------------------------------------------
__global__ __launch_bounds__(256) void k_spmm(
    const int* __restrict__ ofs_s, const int* __restrict__ ofs_e,
    const u32* __restrict__ epak,
    const u16* __restrict__ ya, const u16* __restrict__ yb, const u16* __restrict__ yc,
    const float* __restrict__ uv, FuseW FW) {
  __shared__ u16 Asm[16 * 264];                // [16 rows][256 + 8 pad]
  int tid = threadIdx.x;
  int lane = tid & 63, wid = tid >> 6;
  int g = lane >> 4, gl = lane & 15;
  const u32 glb = (u32)gl * 16;                // byte offset within 256B feature row
  int lr = wid * 4 + g;                        // local row 0..15
  int row = blockIdx.x * 16 + lr;              // 3125 * 16 = 50000 exactly
  int gy = blockIdx.y;
  if (gy == 0) {
    const char* ybase = (const char*)yb;
    const char* cbase = (const char*)yc;
    f32x2 fb2[4] = {}; f32x2 fc2[4] = {};
    {
      int i = ofs_s[row], e = ofs_e[row];
      for (; i + 4 <= e; i += 4) {
        u32 p0 = epak[i], p1 = epak[i + 1], p2 = epak[i + 2], p3 = epak[i + 3];
        uint4 q0 = *(const uint4*)(ybase + (((p0 & 0xFFFFu) << 9) + glb));
        uint4 q1 = *(const uint4*)(ybase + (((p1 & 0xFFFFu) << 9) + glb));
        uint4 q2 = *(const uint4*)(ybase + (((p2 & 0xFFFFu) << 9) + glb));
        uint4 q3 = *(const uint4*)(ybase + (((p3 & 0xFFFFu) << 9) + glb));
        accp8(fb2, q0, __uint_as_float(p0 & 0xffff0000u));
        accp8(fb2, q1, __uint_as_float(p1 & 0xffff0000u));
        accp8(fb2, q2, __uint_as_float(p2 & 0xffff0000u));
        accp8(fb2, q3, __uint_as_float(p3 & 0xffff0000u));
      }
      for (; i < e; ++i) {
        u32 p0 = epak[i];
        uint4 q0 = *(const uint4*)(ybase + (((p0 & 0xFFFFu) << 9) + glb));
        accp8(fb2, q0, __uint_as_float(p0 & 0xffff0000u));
      }
    }
    {
      const u32* pr = epak + BSTRIDE;
      int i = ofs_s[NA + row], e = ofs_e[NA + row];
      for (; i + 4 <= e; i += 4) {
        u32 p0 = pr[i], p1 = pr[i + 1], p2 = pr[i + 2], p3 = pr[i + 3];
        uint4 q0 = *(const uint4*)(cbase + (((p0 & 0xFFFFu) << 9) + glb));
        uint4 q1 = *(const uint4*)(cbase + (((p1 & 0xFFFFu) << 9) + glb));
        uint4 q2 = *(const uint4*)(cbase + (((p2 & 0xFFFFu) << 9) + glb));
        uint4 q3 = *(const uint4*)(cbase + (((p3 & 0xFFFFu) << 9) + glb));
        accp8(fc2, q0, __uint_as_float(p0 & 0xffff0000u));
        accp8(fc2, q1, __uint_as_float(p1 & 0xffff0000u));
        accp8(fc2, q2, __uint_as_float(p2 & 0xffff0000u));
        accp8(fc2, q3, __uint_as_float(p3 & 0xffff0000u));
      }
      for (; i < e; ++i) {
        u32 p0 = pr[i];
        uint4 q0 = *(const uint4*)(cbase + (((p0 & 0xFFFFu) << 9) + glb));
        accp8(fc2, q0, __uint_as_float(p0 & 0xffff0000u));
      }
    }
    float fb[8], fc[8];
    #pragma unroll
    for (int j = 0; j < 8; ++j) { fb[j] = fb2[j >> 1][j & 1]; fc[j] = fc2[j >> 1][j & 1]; }
    uint4 sq = *(const uint4*)((const char*)ya + (u32)row * 768 + glb);
    float sf[8];
    sf[0] = __uint_as_float(sq.x << 16); sf[1] = __uint_as_float(sq.x & 0xffff0000u);
    sf[2] = __uint_as_float(sq.y << 16); sf[3] = __uint_as_float(sq.y & 0xffff0000u);
    sf[4] = __uint_as_float(sq.z << 16); sf[5] = __uint_as_float(sq.z & 0xffff0000u);
    sf[6] = __uint_as_float(sq.w << 16); sf[7] = __uint_as_float(sq.w & 0xffff0000u);
    float pb = 0.f, pc = 0.f, pq = 0.f;
    const float* up = uv + gl * 8;
    const float* vp = uv + 128 + gl * 8;
    #pragma unroll
    for (int j = 0; j < 8; ++j) {
      pb += fb[j] * up[j];
      pc += fc[j] * up[j];
      pq += sf[j] * vp[j];
    }
    #pragma unroll
    for (int off = 1; off < 16; off <<= 1) {
      pb += __shfl_xor(pb, off);
      pc += __shfl_xor(pc, off);
      pq += __shfl_xor(pq, off);
    }
    float eb = pb + pq, ec = pc + pq;
    eb = eb > 0.f ? eb : (expf(eb) - 1.f);
    ec = ec > 0.f ? ec : (expf(ec) - 1.f);
    float m = fmaxf(eb, ec);
    float p0 = expf(eb - m), p1 = expf(ec - m);
    float inv = 1.f / (p0 + p1);
    float a0 = p0 * inv, a1 = p1 * inv;
    s16x8 av;
    #pragma unroll
    for (int j = 0; j < 8; ++j) av[j] = (short)f2bf(a0 * fb[j] + a1 * fc[j]);
    *(s16x8*)&Asm[lr * 264 + gl * 8] = av;                 // agg -> cols 0..127
    *(s16x8*)&Asm[lr * 264 + 128 + gl * 8] = *(s16x8*)&sq; // self -> cols 128..255
  } else {
    const int which = gy - 1;                 // 0 -> ba, 1 -> ca
    const int* os = ofs_s + (2 + which) * NA;
    const int* oe = ofs_e + (2 + which) * NA;
    const u32* pr = epak + (size_t)(2 + which) * BSTRIDE;
    const char* fbase = (const char*)ya + (which ? 512 : 256);  // ld = 768 B
    const char* selfp = (const char*)(which ? yc : yb);         // ld = 512 B
    f32x2 fa2[4] = {};
    int i = os[row], e = oe[row];
    for (; i + 4 <= e; i += 4) {
      u32 p0 = pr[i], p1 = pr[i + 1], p2 = pr[i + 2], p3 = pr[i + 3];
      uint4 q0 = *(const uint4*)(fbase + ((p0 & 0xFFFFu) * 768u + glb));
      uint4 q1 = *(const uint4*)(fbase + ((p1 & 0xFFFFu) * 768u + glb));
      uint4 q2 = *(const uint4*)(fbase + ((p2 & 0xFFFFu) * 768u + glb));
      uint4 q3 = *(const uint4*)(fbase + ((p3 & 0xFFFFu) * 768u + glb));
      accp8(fa2, q0, __uint_as_float(p0 & 0xffff0000u));
      accp8(fa2, q1, __uint_as_float(p1 & 0xffff0000u));
      accp8(fa2, q2, __uint_as_float(p2 & 0xffff0000u));
      accp8(fa2, q3, __uint_as_float(p3 & 0xffff0000u));
    }
    for (; i < e; ++i) {
      u32 p0 = pr[i];
      uint4 q0 = *(const uint4*)(fbase + ((p0 & 0xFFFFu) * 768u + glb));
      accp8(fa2, q0, __uint_as_float(p0 & 0xffff0000u));
    }
    s16x8 av;
    #pragma unroll
    for (int j = 0; j < 8; ++j) av[j] = (short)f2bf(fa2[j >> 1][j & 1]);
    *(s16x8*)&Asm[lr * 264 + gl * 8] = av;                 // agg -> cols 0..127
    *(s16x8*)&Asm[lr * 264 + 128 + gl * 8] =
        *(const s16x8*)(selfp + (u32)row * 512 + 256 + glb); // self (already bf16)
  }
  __syncthreads();
  // ---------------- fused output GEMM epilogue ----------------
  // wave `wid` computes output cols [wid*32, wid*32+32) for all 16 rows.
  const u16* Wf = FW.Wf[gy];
  const float* bias = FW.bias[gy];
  float* outp = FW.out[gy];
  const int j0 = wid * 2, j1 = wid * 2 + 1;
  f32x4 acc0 = {0.f, 0.f, 0.f, 0.f}, acc1 = {0.f, 0.f, 0.f, 0.f};
  #pragma unroll
  for (int ks = 0; ks < 8; ++ks) {
    s16x8 a = *(const s16x8*)&Asm[(lane & 15) * 264 + ks * 32 + (lane >> 4) * 8];
    s16x8 b0 = *(const s16x8*)(Wf + ((size_t)(ks * 8 + j0) * 64 + lane) * 8);
    s16x8 b1 = *(const s16x8*)(Wf + ((size_t)(ks * 8 + j1) * 64 + lane) * 8);
    acc0 = __builtin_amdgcn_mfma_f32_16x16x32_bf16(a, b0, acc0, 0, 0, 0);
    acc1 = __builtin_amdgcn_mfma_f32_16x16x32_bf16(a, b1, acc1, 0, 0, 0);
  }
  const int c0 = j0 * 16 + (lane & 15), c1 = j1 * 16 + (lane & 15);
  const float b0v = bias[c0], b1v = bias[c1];
  const int rbase = blockIdx.x * 16 + (lane >> 4) * 4;
  #pragma unroll
  for (int q = 0; q < 4; ++q) {
    __builtin_nontemporal_store(acc0[q] + b0v, &outp[(size_t)(rbase + q) * 128 + c0]);
    __builtin_nontemporal_store(acc1[q] + b1v, &outp[(size_t)(rbase + q) * 128 + c1]);
  }
}

// ---------------------------------------------------------------------------
extern "C" void kernel_launch(void* const* d_in, const int* in_sizes, int n_in,
                              void* d_out, int out_size, void* d_ws, size_t ws_size,
                              hipStream_t stream) {
  const float* x_a = (const float*)d_in[0];
  const float* x_b = (const float*)d_in[1];
  const float* x_c = (const float*)d_in[2];
  const int* row_ab = (const int*)d_in[3];
  const int* col_ab = (const int*)d_in[4];
  const float* val_ab = (const float*)d_in[5];
  const int* row_ac = (const int*)d_in[6];
  const int* col_ac = (const int*)d_in[7];
  const float* val_ac = (const float*)d_in[8];
  const int* row_ba = (const int*)d_in[9];
  const int* col_ba = (const int*)d_in[10];
  const float* val_ba = (const float*)d_in[11];
  const int* row_ca = (const int*)d_in[12];
  const int* col_ca = (const int*)d_in[13];
  const float* val_ca = (const float*)d_in[14];
  const float* w_self_a = (const float*)d_in[15];
  const float* w_self_b = (const float*)d_in[16];
  const float* w_self_c = (const float*)d_in[17];
  const float* W_ab = (const float*)d_in[18];
  const float* W_ac = (const float*)d_in[19];
  const float* W_ba = (const float*)d_in[20];
  const float* W_ca = (const float*)d_in[21];
  const float* bias_a = (const float*)d_in[22];
  const float* bias_b = (const float*)d_in[23];
  const float* bias_c = (const float*)d_in[24];
  const float* w_cat_a = (const float*)d_in[25];
  const float* w_cat_b = (const float*)d_in[26];
  const float* w_cat_c = (const float*)d_in[27];
  const float* w_query_a = (const float*)d_in[28];
  const float* w_keys_a = (const float*)d_in[29];
  const float* w_att_a = (const float*)d_in[30];

  float* out = (float*)d_out;

  // ---- workspace layout ----
  char* ws = (char*)d_ws;
  size_t off_b = 0;
  auto walloc = [&](size_t bytes) {
    void* p = ws + off_b;
    off_b = (off_b + bytes + 255) & ~(size_t)255;
    return p;
  };
  u16* ya = (u16*)walloc((size_t)NA * 384 * 2);     // [self_a | fa_ba | fa_ca]
  u16* yb = (u16*)walloc((size_t)NA * 256 * 2);     // [fb | self_b]
  u16* yc = (u16*)walloc((size_t)NA * 256 * 2);     // [fc | self_c]
  int* ofs_s = (int*)walloc((size_t)4 * NA * 4);
  int* ofs_e = (int*)walloc((size_t)4 * NA * 4);
  u32* gcur = (u32*)walloc((size_t)4 * 256 * 4);
  uint2* pairs = (uint2*)walloc((size_t)4 * BSTRIDE * 8);
  u32* epak = (u32*)walloc((size_t)4 * BSTRIDE * 4);
  u16* Wa_t = (u16*)walloc((size_t)384 * 256 * 2);
  u16* Wb_t = (u16*)walloc((size_t)256 * 256 * 2);
  u16* Wc_t = (u16*)walloc((size_t)256 * 256 * 2);
  u16* Wcat_a = (u16*)walloc((size_t)128 * 256 * 2);  // frag-order
  u16* Wcat_b = (u16*)walloc((size_t)128 * 256 * 2);  // frag-order
  u16* Wcat_c = (u16*)walloc((size_t)128 * 256 * 2);  // frag-order
  float* uvbuf = (float*)walloc(256 * 4);
  u16* xb = (u16*)walloc((size_t)3 * NA * 256 * 2); // bf16 copies of x_a|x_b|x_c

  // relation order: 0=ab, 1=ac, 2=ba, 3=ca
  Rel4 R;
  R.row[0] = row_ab; R.col[0] = col_ab; R.val[0] = val_ab;
  R.row[1] = row_ac; R.col[1] = col_ac; R.val[1] = val_ac;
  R.row[2] = row_ba; R.col[2] = col_ba; R.val[2] = val_ba;
  R.row[3] = row_ca; R.col[3] = col_ca; R.val[3] = val_ca;

  Prep P;
  P.src[0] = w_self_a; P.dst[0] = Wa_t;
  P.src[1] = W_ba;     P.dst[1] = Wa_t + 128 * 256;
  P.src[2] = W_ca;     P.dst[2] = Wa_t + 256 * 256;
  P.src[3] = W_ab;     P.dst[3] = Wb_t;
  P.src[4] = w_self_b; P.dst[4] = Wb_t + 128 * 256;
  P.src[5] = W_ac;     P.dst[5] = Wc_t;
  P.src[6] = w_self_c; P.dst[6] = Wc_t + 128 * 256;
  P.src[7] = w_cat_a;  P.dst[7] = Wcat_a;   // frag-order emit
  P.src[8] = w_cat_b;  P.dst[8] = Wcat_b;   // frag-order emit
  P.src[9] = w_cat_c;  P.dst[9] = Wcat_c;   // frag-order emit
  P.wq = w_query_a; P.wk = w_keys_a; P.wa = w_att_a; P.uvp = uvbuf;

  // ---- gcur counts -> 0 ----
  hipMemsetAsync(gcur, 0, (size_t)4 * 256 * 4, stream);

  // ---- binA ∥ x->bf16 conversion ∥ prep (weights + uv) ----
  ConvArgs CA;
  CA.x[0] = x_a; CA.x[1] = x_b; CA.x[2] = x_c;
  CA.xb = xb;
  dim3 g1(391, 12);
  k_main1<<<g1, 256, 0, stream>>>(R, gcur, pairs, CA, P);

  // ---- binB OVERLAPPED with all 7 feature-GEMM col-tiles (bf16 A, glds) ----
  FtArgs FA;
  FA.A[0] = xb; FA.A[1] = xb + (size_t)NA * 256; FA.A[2] = xb + (size_t)2 * NA * 256;
  FA.Bt[0] = Wa_t; FA.Bt[1] = Wb_t; FA.Bt[2] = Wc_t;
  FA.C[0] = ya; FA.C[1] = yb; FA.C[2] = yc;
  dim3 g2(391, 11);
  k_main2<<<g2, 256, 0, stream>>>(gcur, ofs_s, ofs_e, pairs, epak, FA);

  // ---- fused SpMMs + output GEMMs ----
  FuseW FW;
  FW.Wf[0] = Wcat_a; FW.Wf[1] = Wcat_b; FW.Wf[2] = Wcat_c;
  FW.bias[0] = bias_a; FW.bias[1] = bias_b; FW.bias[2] = bias_c;
  FW.out[0] = out; FW.out[1] = out + (size_t)NA * 128; FW.out[2] = out + (size_t)NA * 128 * 2;
  dim3 gs(3125, 3);
  k_spmm<<<gs, 256, 0, stream>>>(ofs_s, ofs_e, epak, ya, yb, yc, uvbuf, FW);
}